// Round 12
// baseline (296.429 us; speedup 1.0000x reference)
//
#include <hip/hip_runtime.h>
#include <hip/hip_bf16.h>

#define NN 100000
#define NE 1600000
#define NC 800000
#define D  32
#define DE 65
#define JB 64     // bf16 elements per table row: 128B, line-aligned; 8 uint4
#define KP 33     // LDS k-stride in precompute (conflict-free)
#define W1_LD 68  // fallback kernel stride
#define NT (NE / 16)   // 100000 full 16-edge tiles (NE % 16 == 0)

// ---- ws byte offsets (128B-aligned tables) ----
#define OFF_A   0u                  // bf16[NN*64]  A table (b1 folded), 128B rows
#define OFF_B   12800000u           // bf16[NN*64]  B table
#define OFF_A64 25600000u           // bf16[NN]     A j=64 column (b1[64] folded)
#define OFF_B64 25800000u           // bf16[NN]     B j=64 column
#define OFF_H64 26000000u           // bf16[NE]     per-edge hidden j=64 (post-selu)
#define WS_NEED 29200000u

typedef __attribute__((ext_vector_type(8))) short short8;
typedef __attribute__((ext_vector_type(4))) float f32x4;

__device__ __forceinline__ float selu_f(float x) {
    // branch-free: x>0 -> scale*x ; x<0 -> scale*alpha*(exp(x)-1)
    float p = fmaxf(x, 0.f);
    float m = fminf(x, 0.f);
    return fmaf(1.7580993408473766f, __expf(m) - 1.f, 1.0507009873554805f * p);
}

__device__ __forceinline__ float2 bf2(unsigned int u) {
    // two packed bf16 -> two floats (element 0 in low 16 bits)
    return make_float2(__uint_as_float(u << 16), __uint_as_float(u & 0xffff0000u));
}

__device__ __forceinline__ float bfs(unsigned short u) {
    return __uint_as_float(((unsigned)u) << 16);
}

__device__ __forceinline__ short f2bf(float x) {
    union { __hip_bfloat16 h; short s; } u;
    u.h = __float2bfloat16(x);
    return u.s;
}

// ---------------- per-node layer-1 halves (j<64), bf16, 128B rows ----------------
// A[n][j] = b1[j] + sum_k h[n][k]*W1[k][j]      (k in [0,32))
// B[n][j] =          sum_k h[n][k]*W1[32+k][j]
__global__ __launch_bounds__(256) void precompute_kernel(
    const float* __restrict__ h, const float* __restrict__ W1,
    const float* __restrict__ b1,
    __hip_bfloat16* __restrict__ A, __hip_bfloat16* __restrict__ B)
{
    __shared__ float sWA[JB * KP];
    __shared__ float sWB[JB * KP];
    __shared__ float sb1[JB];
    for (int i = threadIdx.x; i < JB * 32; i += 256) {
        int j = i >> 5, k = i & 31;
        sWA[j * KP + k] = W1[k * DE + j];
        sWB[j * KP + k] = W1[(k + 32) * DE + j];
    }
    if (threadIdx.x < JB) sb1[threadIdx.x] = b1[threadIdx.x];
    __syncthreads();

    const int idx = blockIdx.x * 256 + threadIdx.x;   // grid covers NN*JB exactly
    const int n = idx >> 6;
    const int j = idx & 63;
    const float4* hr = reinterpret_cast<const float4*>(h + (size_t)n * D);
    const float* wa = &sWA[j * KP];
    const float* wb = &sWB[j * KP];
    float a = sb1[j], b = 0.f;
    #pragma unroll
    for (int kk = 0; kk < 8; ++kk) {
        float4 hv = hr[kk];
        a = fmaf(hv.x, wa[4*kk+0], a); a = fmaf(hv.y, wa[4*kk+1], a);
        a = fmaf(hv.z, wa[4*kk+2], a); a = fmaf(hv.w, wa[4*kk+3], a);
        b = fmaf(hv.x, wb[4*kk+0], b); b = fmaf(hv.y, wb[4*kk+1], b);
        b = fmaf(hv.z, wb[4*kk+2], b); b = fmaf(hv.w, wb[4*kk+3], b);
    }
    A[idx] = __float2bfloat16(a);
    B[idx] = __float2bfloat16(b);
}

// ---------------- j=64 node columns (bf16 side tables, L2-resident) ----------------
__global__ __launch_bounds__(256) void precompute64_kernel(
    const float* __restrict__ h, const float* __restrict__ W1,
    const float* __restrict__ b1,
    unsigned short* __restrict__ A64, unsigned short* __restrict__ B64)
{
    __shared__ float w1a[32], w1b[32];
    if (threadIdx.x < 32) {
        w1a[threadIdx.x] = W1[threadIdx.x * DE + 64];
        w1b[threadIdx.x] = W1[(threadIdx.x + 32) * DE + 64];
    }
    __syncthreads();
    const int n = blockIdx.x * 256 + threadIdx.x;
    if (n >= NN) return;
    const float4* hr = reinterpret_cast<const float4*>(h + (size_t)n * D);
    float a = b1[64], b = 0.f;
    #pragma unroll
    for (int kk = 0; kk < 8; ++kk) {
        float4 hv = hr[kk];
        a = fmaf(hv.x, w1a[4*kk+0], a); a = fmaf(hv.y, w1a[4*kk+1], a);
        a = fmaf(hv.z, w1a[4*kk+2], a); a = fmaf(hv.w, w1a[4*kk+3], a);
        b = fmaf(hv.x, w1b[4*kk+0], b); b = fmaf(hv.y, w1b[4*kk+1], b);
        b = fmaf(hv.z, w1b[4*kk+2], b); b = fmaf(hv.w, w1b[4*kk+3], b);
    }
    A64[n] = (unsigned short)f2bf(a);
    B64[n] = (unsigned short)f2bf(b);
}

// ---------------- per-edge h64 = selu(A64[r]+B64[s]+c*w) (coalesced write) ----------
__global__ __launch_bounds__(256) void h64_kernel(
    const int* __restrict__ senders, const int* __restrict__ receivers,
    const float* __restrict__ coup,
    const unsigned short* __restrict__ A64, const unsigned short* __restrict__ B64,
    const float* __restrict__ W1,
    unsigned short* __restrict__ H64)
{
    const int e = blockIdx.x * 256 + threadIdx.x;    // grid covers NE exactly
    const float w64 = W1[64 * DE + 64];
    const int r = receivers[e];
    const int s = senders[e];
    const float c = coup[e < NC ? e : e - NC];
    H64[e] = (unsigned short)f2bf(selu_f(fmaf(c, w64, bfs(A64[r]) + bfs(B64[s]))));
}

// ---------------- edge-order MFMA kernel: one wave per 16-edge tile ----------------
// Lane (er=lane&15, g=lane>>4): builds hidden units j=32c+8g+i for edge er (A-frag),
// W2 register-resident B-frags; C/D: col=lane&15 (output dim), row=4g+reg (edge).
// j=64 rank-1 term via precomputed H64 (coalesced) + shfl. bf16 tables: 128B rows,
// one line per row gather. Unsorted atomics: 64 distinct addresses per wave-inst.
__global__ __launch_bounds__(256) void edge_mfma_kernel(
    const int* __restrict__ senders,
    const int* __restrict__ receivers,
    const float* __restrict__ coup,
    const uint4* __restrict__ Au4,
    const uint4* __restrict__ Bu4,
    const unsigned short* __restrict__ H64,
    const float* __restrict__ W1,
    const float* __restrict__ W2,
    const float* __restrict__ b2,
    float* __restrict__ out)
{
    const int lane = threadIdx.x & 63;
    const int g    = lane >> 4;              // k-octet group
    const int er   = lane & 15;              // edge slot / output col

    // ---- per-wave hoisted constants (amortized over ~12 tiles) ----
    float w1c0[8], w1c1[8];
    #pragma unroll
    for (int i = 0; i < 8; ++i) {
        w1c0[i] = W1[64 * DE + 8 * g + i];
        w1c1[i] = W1[64 * DE + 32 + 8 * g + i];
    }

    short8 WB[2][2];   // WB[chunk][colhalf][i] = W2[32c+8g+i][16hf+er]
    #pragma unroll
    for (int c = 0; c < 2; ++c)
        #pragma unroll
        for (int hf = 0; hf < 2; ++hf)
            #pragma unroll
            for (int i = 0; i < 8; ++i)
                WB[c][hf][i] = f2bf(W2[(32 * c + 8 * g + i) * D + 16 * hf + er]);
    const float w2_64lo = W2[64 * D + er];
    const float w2_64hi = W2[64 * D + 16 + er];
    const float b2lo = b2[er];
    const float b2hi = b2[16 + er];

    int tile = blockIdx.x * 4 + (threadIdx.x >> 6);
    const int stride = gridDim.x * 4;
    if (tile >= NT) return;

    // ---- prologue: indices + gathers for first tile ----
    int e = tile * 16 + er;
    int s = senders[e];
    int r = receivers[e];
    float ce = coup[e < NC ? e : e - NC];
    uint4 av0 = Au4[(size_t)r * 8 + g];
    uint4 av1 = Au4[(size_t)r * 8 + 4 + g];
    uint4 bv0 = Bu4[(size_t)s * 8 + g];
    uint4 bv1 = Bu4[(size_t)s * 8 + 4 + g];
    unsigned short h64u = H64[e];

    while (true) {
        // ---- prefetch next tile's indices (overlaps current compute) ----
        const int tn = tile + stride;
        const bool more = tn < NT;
        int sn = 0, rn = 0;
        float cn = 0.f;
        unsigned short h64n = 0;
        if (more) {
            const int en = tn * 16 + er;
            sn = senders[en];
            rn = receivers[en];
            cn = coup[en < NC ? en : en - NC];
            h64n = H64[en];
        }

        // ---- build A-frags for current tile ----
        short8 A0, A1;
        {
            float2 ta, tb;
            ta = bf2(av0.x); tb = bf2(bv0.x);
            A0[0] = f2bf(selu_f(fmaf(ce, w1c0[0], ta.x + tb.x)));
            A0[1] = f2bf(selu_f(fmaf(ce, w1c0[1], ta.y + tb.y)));
            ta = bf2(av0.y); tb = bf2(bv0.y);
            A0[2] = f2bf(selu_f(fmaf(ce, w1c0[2], ta.x + tb.x)));
            A0[3] = f2bf(selu_f(fmaf(ce, w1c0[3], ta.y + tb.y)));
            ta = bf2(av0.z); tb = bf2(bv0.z);
            A0[4] = f2bf(selu_f(fmaf(ce, w1c0[4], ta.x + tb.x)));
            A0[5] = f2bf(selu_f(fmaf(ce, w1c0[5], ta.y + tb.y)));
            ta = bf2(av0.w); tb = bf2(bv0.w);
            A0[6] = f2bf(selu_f(fmaf(ce, w1c0[6], ta.x + tb.x)));
            A0[7] = f2bf(selu_f(fmaf(ce, w1c0[7], ta.y + tb.y)));
            ta = bf2(av1.x); tb = bf2(bv1.x);
            A1[0] = f2bf(selu_f(fmaf(ce, w1c1[0], ta.x + tb.x)));
            A1[1] = f2bf(selu_f(fmaf(ce, w1c1[1], ta.y + tb.y)));
            ta = bf2(av1.y); tb = bf2(bv1.y);
            A1[2] = f2bf(selu_f(fmaf(ce, w1c1[2], ta.x + tb.x)));
            A1[3] = f2bf(selu_f(fmaf(ce, w1c1[3], ta.y + tb.y)));
            ta = bf2(av1.z); tb = bf2(bv1.z);
            A1[4] = f2bf(selu_f(fmaf(ce, w1c1[4], ta.x + tb.x)));
            A1[5] = f2bf(selu_f(fmaf(ce, w1c1[5], ta.y + tb.y)));
            ta = bf2(av1.w); tb = bf2(bv1.w);
            A1[6] = f2bf(selu_f(fmaf(ce, w1c1[6], ta.x + tb.x)));
            A1[7] = f2bf(selu_f(fmaf(ce, w1c1[7], ta.y + tb.y)));
        }
        const float h64 = bfs(h64u);
        const int rcur = r;

        // ---- issue next tile's gathers (latency hides under MFMA+epilogue) ----
        uint4 av0n, av1n, bv0n, bv1n;
        if (more) {
            av0n = Au4[(size_t)rn * 8 + g];
            av1n = Au4[(size_t)rn * 8 + 4 + g];
            bv0n = Bu4[(size_t)sn * 8 + g];
            bv1n = Bu4[(size_t)sn * 8 + 4 + g];
        }

        // ---- MFMA: (16 edges) x 32 dims, K=64 ----
        f32x4 Clo = {0.f, 0.f, 0.f, 0.f};
        f32x4 Chi = {0.f, 0.f, 0.f, 0.f};
        Clo = __builtin_amdgcn_mfma_f32_16x16x32_bf16(A0, WB[0][0], Clo, 0, 0, 0);
        Clo = __builtin_amdgcn_mfma_f32_16x16x32_bf16(A1, WB[1][0], Clo, 0, 0, 0);
        Chi = __builtin_amdgcn_mfma_f32_16x16x32_bf16(A0, WB[0][1], Chi, 0, 0, 0);
        Chi = __builtin_amdgcn_mfma_f32_16x16x32_bf16(A1, WB[1][1], Chi, 0, 0, 0);

        // ---- j=64 fold + outer selu + atomic scatter ----
        #pragma unroll
        for (int q = 0; q < 4; ++q) {
            const int m = 4 * g + q;                 // edge slot of C row q
            const float hm = __shfl(h64, m);
            const int   rq = __shfl(rcur, m);
            const float mlo = selu_f(fmaf(hm, w2_64lo, Clo[q]) + b2lo);
            const float mhi = selu_f(fmaf(hm, w2_64hi, Chi[q]) + b2hi);
            unsafeAtomicAdd(&out[(size_t)rq * D + er], mlo);
            unsafeAtomicAdd(&out[(size_t)rq * D + 16 + er], mhi);
        }

        if (!more) break;
        tile = tn; s = sn; r = rn; ce = cn;
        av0 = av0n; av1 = av1n; bv0 = bv0n; bv1 = bv1n;
        h64u = h64n;
    }
}

__global__ __launch_bounds__(256) void relu_kernel(float* __restrict__ out) {
    const int i = blockIdx.x * 256 + threadIdx.x;
    float4* p = reinterpret_cast<float4*>(out);
    float4 v = p[i];
    v.x = fmaxf(v.x, 0.f); v.y = fmaxf(v.y, 0.f);
    v.z = fmaxf(v.z, 0.f); v.w = fmaxf(v.w, 0.f);
    p[i] = v;
}

// ---------------- fallback (ws too small): monolithic round-1 kernel ----------
__global__ __launch_bounds__(256) void edge_msg_fallback(
    const float* __restrict__ h, const float* __restrict__ coup,
    const float* __restrict__ W1, const float* __restrict__ b1,
    const float* __restrict__ W2, const float* __restrict__ b2,
    const int* __restrict__ senders, const int* __restrict__ receivers,
    float* __restrict__ out)
{
    __shared__ float sW1t[DE * W1_LD];
    __shared__ float sW2[DE * D];
    __shared__ float sb1[DE];
    __shared__ float sb2[D];
    for (int i = threadIdx.x; i < DE * DE; i += 256) {
        int k = i / DE, j = i - k * DE;
        sW1t[j * W1_LD + k] = W1[i];
    }
    for (int i = threadIdx.x; i < DE * D; i += 256) sW2[i] = W2[i];
    if (threadIdx.x < DE) sb1[threadIdx.x] = b1[threadIdx.x];
    if (threadIdx.x >= 128 && threadIdx.x < 128 + D) sb2[threadIdx.x - 128] = b2[threadIdx.x - 128];
    __syncthreads();
    const int e = blockIdx.x * 256 + threadIdx.x;
    const int s = senders[e];
    const int r = receivers[e];
    float edgef[DE];
    const float4* hr = reinterpret_cast<const float4*>(h + (size_t)r * D);
    const float4* hs = reinterpret_cast<const float4*>(h + (size_t)s * D);
    #pragma unroll
    for (int i = 0; i < 8; ++i) {
        float4 v = hr[i];
        edgef[4*i] = v.x; edgef[4*i+1] = v.y; edgef[4*i+2] = v.z; edgef[4*i+3] = v.w;
    }
    #pragma unroll
    for (int i = 0; i < 8; ++i) {
        float4 v = hs[i];
        edgef[D+4*i] = v.x; edgef[D+4*i+1] = v.y; edgef[D+4*i+2] = v.z; edgef[D+4*i+3] = v.w;
    }
    edgef[2*D] = coup[e < NC ? e : e - NC];
    float acc[D];
    #pragma unroll
    for (int d2 = 0; d2 < D; ++d2) acc[d2] = sb2[d2];
    for (int j = 0; j < DE; ++j) {
        const float* wrow = &sW1t[j * W1_LD];
        float p0 = 0.f, p1 = 0.f, p2 = 0.f, p3 = 0.f;
        #pragma unroll
        for (int k = 0; k < 64; k += 4) {
            p0 = fmaf(edgef[k], wrow[k], p0);
            p1 = fmaf(edgef[k+1], wrow[k+1], p1);
            p2 = fmaf(edgef[k+2], wrow[k+2], p2);
            p3 = fmaf(edgef[k+3], wrow[k+3], p3);
        }
        float hj = selu_f(sb1[j] + fmaf(edgef[64], wrow[64], (p0+p1)+(p2+p3)));
        const float* w2row = &sW2[j * D];
        #pragma unroll
        for (int d2 = 0; d2 < D; ++d2) acc[d2] = fmaf(hj, w2row[d2], acc[d2]);
    }
    float* op = out + (size_t)r * D;
    #pragma unroll
    for (int d2 = 0; d2 < D; ++d2) unsafeAtomicAdd(op + d2, selu_f(acc[d2]));
}

extern "C" void kernel_launch(void* const* d_in, const int* in_sizes, int n_in,
                              void* d_out, int out_size, void* d_ws, size_t ws_size,
                              hipStream_t stream) {
    const float* h    = (const float*)d_in[0];
    const float* coup = (const float*)d_in[1];
    const float* W1   = (const float*)d_in[2];
    const float* b1   = (const float*)d_in[3];
    const float* W2   = (const float*)d_in[4];
    const float* b2   = (const float*)d_in[5];
    // d_in[6..9] = Wq, bq, Wk, bk: unused — softmax over a size-1 axis is 1.0
    const int* senders   = (const int*)d_in[10];
    const int* receivers = (const int*)d_in[11];
    float* out = (float*)d_out;

    hipMemsetAsync(d_out, 0, (size_t)out_size * sizeof(float), stream);

    if (ws_size >= (size_t)WS_NEED) {
        char* ws = (char*)d_ws;
        __hip_bfloat16* Atab = (__hip_bfloat16*)(ws + OFF_A);
        __hip_bfloat16* Btab = (__hip_bfloat16*)(ws + OFF_B);
        unsigned short* A64  = (unsigned short*)(ws + OFF_A64);
        unsigned short* B64  = (unsigned short*)(ws + OFF_B64);
        unsigned short* H64  = (unsigned short*)(ws + OFF_H64);

        precompute_kernel<<<NN * JB / 256, 256, 0, stream>>>(h, W1, b1, Atab, Btab);
        precompute64_kernel<<<(NN + 255) / 256, 256, 0, stream>>>(h, W1, b1, A64, B64);
        h64_kernel<<<NE / 256, 256, 0, stream>>>(senders, receivers, coup, A64, B64, W1, H64);
        edge_mfma_kernel<<<2048, 256, 0, stream>>>(
            senders, receivers, coup,
            (const uint4*)Atab, (const uint4*)Btab, H64,
            W1, W2, b2, out);
    } else {
        edge_msg_fallback<<<NE / 256, 256, 0, stream>>>(
            h, coup, W1, b1, W2, b2, senders, receivers, out);
    }
    relu_kernel<<<out_size / 4 / 256, 256, 0, stream>>>(out);
}

// Round 13
// 206.131 us; speedup vs baseline: 1.4381x; 1.4381x over previous
//
#include <hip/hip_runtime.h>
#include <hip/hip_bf16.h>
#include <hip/hip_fp16.h>

#define NN 100000
#define NE 1600000
#define NC 800000
#define D  32
#define DE 65
#define JB 64     // bf16 elements per table row: 128B, line-aligned; 8 uint4
#define KP 33     // LDS k-stride in precompute (conflict-free)
#define W1_LD 68  // fallback kernel stride
#define NT (NE / 16)   // 100000 full 16-edge tiles (NE % 16 == 0)

// ---- ws byte offsets (128B-aligned tables) ----
#define OFF_A   0u                  // bf16[NN*64]  A table (b1 folded), 128B rows
#define OFF_B   12800000u           // bf16[NN*64]  B table
#define OFF_A64 25600000u           // bf16[NN]     A j=64 column (b1[64] folded)
#define OFF_B64 25800000u           // bf16[NN]     B j=64 column
#define OFF_AGG 26000000u           // f16[NN*32]   packed-atomic accumulator
#define WS_NEED 32400000u

typedef __attribute__((ext_vector_type(8))) short short8;
typedef __attribute__((ext_vector_type(4))) float f32x4;

__device__ __forceinline__ float selu_f(float x) {
    // branch-free: x>0 -> scale*x ; x<0 -> scale*alpha*(exp(x)-1)
    float p = fmaxf(x, 0.f);
    float m = fminf(x, 0.f);
    return fmaf(1.7580993408473766f, __expf(m) - 1.f, 1.0507009873554805f * p);
}

__device__ __forceinline__ float2 bf2(unsigned int u) {
    // two packed bf16 -> two floats (element 0 in low 16 bits)
    return make_float2(__uint_as_float(u << 16), __uint_as_float(u & 0xffff0000u));
}

__device__ __forceinline__ float bfs(unsigned short u) {
    return __uint_as_float(((unsigned)u) << 16);
}

__device__ __forceinline__ short f2bf(float x) {
    union { __hip_bfloat16 h; short s; } u;
    u.h = __float2bfloat16(x);
    return u.s;
}

// ---------------- per-node layer-1 halves (j<64), bf16, 128B rows ----------------
// A[n][j] = b1[j] + sum_k h[n][k]*W1[k][j]      (k in [0,32))
// B[n][j] =          sum_k h[n][k]*W1[32+k][j]
__global__ __launch_bounds__(256) void precompute_kernel(
    const float* __restrict__ h, const float* __restrict__ W1,
    const float* __restrict__ b1,
    __hip_bfloat16* __restrict__ A, __hip_bfloat16* __restrict__ B)
{
    __shared__ float sWA[JB * KP];
    __shared__ float sWB[JB * KP];
    __shared__ float sb1[JB];
    for (int i = threadIdx.x; i < JB * 32; i += 256) {
        int j = i >> 5, k = i & 31;
        sWA[j * KP + k] = W1[k * DE + j];
        sWB[j * KP + k] = W1[(k + 32) * DE + j];
    }
    if (threadIdx.x < JB) sb1[threadIdx.x] = b1[threadIdx.x];
    __syncthreads();

    const int idx = blockIdx.x * 256 + threadIdx.x;   // grid covers NN*JB exactly
    const int n = idx >> 6;
    const int j = idx & 63;
    const float4* hr = reinterpret_cast<const float4*>(h + (size_t)n * D);
    const float* wa = &sWA[j * KP];
    const float* wb = &sWB[j * KP];
    float a = sb1[j], b = 0.f;
    #pragma unroll
    for (int kk = 0; kk < 8; ++kk) {
        float4 hv = hr[kk];
        a = fmaf(hv.x, wa[4*kk+0], a); a = fmaf(hv.y, wa[4*kk+1], a);
        a = fmaf(hv.z, wa[4*kk+2], a); a = fmaf(hv.w, wa[4*kk+3], a);
        b = fmaf(hv.x, wb[4*kk+0], b); b = fmaf(hv.y, wb[4*kk+1], b);
        b = fmaf(hv.z, wb[4*kk+2], b); b = fmaf(hv.w, wb[4*kk+3], b);
    }
    A[idx] = __float2bfloat16(a);
    B[idx] = __float2bfloat16(b);
}

// ---------------- j=64 node columns (bf16 side tables, L2-resident) ----------------
__global__ __launch_bounds__(256) void precompute64_kernel(
    const float* __restrict__ h, const float* __restrict__ W1,
    const float* __restrict__ b1,
    unsigned short* __restrict__ A64, unsigned short* __restrict__ B64)
{
    __shared__ float w1a[32], w1b[32];
    if (threadIdx.x < 32) {
        w1a[threadIdx.x] = W1[threadIdx.x * DE + 64];
        w1b[threadIdx.x] = W1[(threadIdx.x + 32) * DE + 64];
    }
    __syncthreads();
    const int n = blockIdx.x * 256 + threadIdx.x;
    if (n >= NN) return;
    const float4* hr = reinterpret_cast<const float4*>(h + (size_t)n * D);
    float a = b1[64], b = 0.f;
    #pragma unroll
    for (int kk = 0; kk < 8; ++kk) {
        float4 hv = hr[kk];
        a = fmaf(hv.x, w1a[4*kk+0], a); a = fmaf(hv.y, w1a[4*kk+1], a);
        a = fmaf(hv.z, w1a[4*kk+2], a); a = fmaf(hv.w, w1a[4*kk+3], a);
        b = fmaf(hv.x, w1b[4*kk+0], b); b = fmaf(hv.y, w1b[4*kk+1], b);
        b = fmaf(hv.z, w1b[4*kk+2], b); b = fmaf(hv.w, w1b[4*kk+3], b);
    }
    A64[n] = (unsigned short)f2bf(a);
    B64[n] = (unsigned short)f2bf(b);
}

// ---------------- edge-order MFMA kernel: one wave per 16-edge tile ----------------
// Lane (er=lane&15, g=lane>>4): builds hidden units j=32c+8g+i for edge er (A-frag),
// W2 register-resident B-frags; C/D: col=lane&15 (output dim), row=4g+reg (edge).
// Epilogue: shfl-pair adjacent columns -> packed f16 atomics (2 values / 4B atomic)
// into the f16 agg workspace -> halves the device-scope atomic write stream.
__global__ __launch_bounds__(256) void edge_mfma_kernel(
    const int* __restrict__ senders,
    const int* __restrict__ receivers,
    const float* __restrict__ coup,
    const uint4* __restrict__ Au4,
    const uint4* __restrict__ Bu4,
    const unsigned short* __restrict__ A64,
    const unsigned short* __restrict__ B64,
    const float* __restrict__ W1,
    const float* __restrict__ W2,
    const float* __restrict__ b2,
    __half* __restrict__ agg)
{
    const int lane = threadIdx.x & 63;
    const int g    = lane >> 4;              // k-octet group
    const int er   = lane & 15;              // edge slot / output col

    // ---- per-wave hoisted constants (amortized over ~12 tiles) ----
    float w1c0[8], w1c1[8];
    #pragma unroll
    for (int i = 0; i < 8; ++i) {
        w1c0[i] = W1[64 * DE + 8 * g + i];
        w1c1[i] = W1[64 * DE + 32 + 8 * g + i];
    }
    const float w1c64 = W1[64 * DE + 64];

    short8 WB[2][2];   // WB[chunk][colhalf][i] = W2[32c+8g+i][16hf+er]
    #pragma unroll
    for (int c = 0; c < 2; ++c)
        #pragma unroll
        for (int hf = 0; hf < 2; ++hf)
            #pragma unroll
            for (int i = 0; i < 8; ++i)
                WB[c][hf][i] = f2bf(W2[(32 * c + 8 * g + i) * D + 16 * hf + er]);
    const float w2_64lo = W2[64 * D + er];
    const float w2_64hi = W2[64 * D + 16 + er];
    const float b2lo = b2[er];
    const float b2hi = b2[16 + er];

    int tile = blockIdx.x * 4 + (threadIdx.x >> 6);
    const int stride = gridDim.x * 4;
    if (tile >= NT) return;

    // ---- prologue: indices + gathers for first tile ----
    int e = tile * 16 + er;
    int s = senders[e];
    int r = receivers[e];
    float ce = coup[e < NC ? e : e - NC];
    uint4 av0 = Au4[(size_t)r * 8 + g];
    uint4 av1 = Au4[(size_t)r * 8 + 4 + g];
    uint4 bv0 = Bu4[(size_t)s * 8 + g];
    uint4 bv1 = Bu4[(size_t)s * 8 + 4 + g];
    unsigned short a64u = A64[r];
    unsigned short b64u = B64[s];

    while (true) {
        // ---- prefetch next tile's indices (overlaps current compute) ----
        const int tn = tile + stride;
        const bool more = tn < NT;
        int sn = 0, rn = 0;
        float cn = 0.f;
        if (more) {
            const int en = tn * 16 + er;
            sn = senders[en];
            rn = receivers[en];
            cn = coup[en < NC ? en : en - NC];
        }

        // ---- build A-frags for current tile ----
        short8 A0, A1;
        {
            float2 ta, tb;
            ta = bf2(av0.x); tb = bf2(bv0.x);
            A0[0] = f2bf(selu_f(fmaf(ce, w1c0[0], ta.x + tb.x)));
            A0[1] = f2bf(selu_f(fmaf(ce, w1c0[1], ta.y + tb.y)));
            ta = bf2(av0.y); tb = bf2(bv0.y);
            A0[2] = f2bf(selu_f(fmaf(ce, w1c0[2], ta.x + tb.x)));
            A0[3] = f2bf(selu_f(fmaf(ce, w1c0[3], ta.y + tb.y)));
            ta = bf2(av0.z); tb = bf2(bv0.z);
            A0[4] = f2bf(selu_f(fmaf(ce, w1c0[4], ta.x + tb.x)));
            A0[5] = f2bf(selu_f(fmaf(ce, w1c0[5], ta.y + tb.y)));
            ta = bf2(av0.w); tb = bf2(bv0.w);
            A0[6] = f2bf(selu_f(fmaf(ce, w1c0[6], ta.x + tb.x)));
            A0[7] = f2bf(selu_f(fmaf(ce, w1c0[7], ta.y + tb.y)));
            ta = bf2(av1.x); tb = bf2(bv1.x);
            A1[0] = f2bf(selu_f(fmaf(ce, w1c1[0], ta.x + tb.x)));
            A1[1] = f2bf(selu_f(fmaf(ce, w1c1[1], ta.y + tb.y)));
            ta = bf2(av1.y); tb = bf2(bv1.y);
            A1[2] = f2bf(selu_f(fmaf(ce, w1c1[2], ta.x + tb.x)));
            A1[3] = f2bf(selu_f(fmaf(ce, w1c1[3], ta.y + tb.y)));
            ta = bf2(av1.z); tb = bf2(bv1.z);
            A1[4] = f2bf(selu_f(fmaf(ce, w1c1[4], ta.x + tb.x)));
            A1[5] = f2bf(selu_f(fmaf(ce, w1c1[5], ta.y + tb.y)));
            ta = bf2(av1.w); tb = bf2(bv1.w);
            A1[6] = f2bf(selu_f(fmaf(ce, w1c1[6], ta.x + tb.x)));
            A1[7] = f2bf(selu_f(fmaf(ce, w1c1[7], ta.y + tb.y)));
        }
        const float h64 = selu_f(fmaf(ce, w1c64, bfs(a64u) + bfs(b64u)));
        const int rcur = r;

        // ---- issue next tile's gathers (latency hides under MFMA+epilogue) ----
        uint4 av0n, av1n, bv0n, bv1n;
        unsigned short a64n = 0, b64n = 0;
        if (more) {
            av0n = Au4[(size_t)rn * 8 + g];
            av1n = Au4[(size_t)rn * 8 + 4 + g];
            bv0n = Bu4[(size_t)sn * 8 + g];
            bv1n = Bu4[(size_t)sn * 8 + 4 + g];
            a64n = A64[rn];
            b64n = B64[sn];
        }

        // ---- MFMA: (16 edges) x 32 dims, K=64 ----
        f32x4 Clo = {0.f, 0.f, 0.f, 0.f};
        f32x4 Chi = {0.f, 0.f, 0.f, 0.f};
        Clo = __builtin_amdgcn_mfma_f32_16x16x32_bf16(A0, WB[0][0], Clo, 0, 0, 0);
        Clo = __builtin_amdgcn_mfma_f32_16x16x32_bf16(A1, WB[1][0], Clo, 0, 0, 0);
        Chi = __builtin_amdgcn_mfma_f32_16x16x32_bf16(A0, WB[0][1], Chi, 0, 0, 0);
        Chi = __builtin_amdgcn_mfma_f32_16x16x32_bf16(A1, WB[1][1], Chi, 0, 0, 0);

        // ---- j=64 fold + outer selu + packed-f16 atomic scatter ----
        #pragma unroll
        for (int q = 0; q < 4; ++q) {
            const int m = 4 * g + q;                 // edge slot of C row q
            const float hm = __shfl(h64, m);
            const int   rq = __shfl(rcur, m);
            const float mlo = selu_f(fmaf(hm, w2_64lo, Clo[q]) + b2lo);
            const float mhi = selu_f(fmaf(hm, w2_64hi, Chi[q]) + b2hi);
            const float pl = __shfl_xor(mlo, 1);     // partner column's lo value
            const float ph = __shfl_xor(mhi, 1);     // partner column's hi value
            __half2 val;
            int off;
            if ((er & 1) == 0) {                     // even lane: cols (er, er+1)
                val = __halves2half2(__float2half(mlo), __float2half(pl));
                off = rq * D + er;
            } else {                                 // odd lane: cols (er+15, er+16)
                val = __halves2half2(__float2half(ph), __float2half(mhi));
                off = rq * D + 16 + (er - 1);
            }
            unsafeAtomicAdd(reinterpret_cast<__half2*>(agg + off), val);
        }

        if (!more) break;
        tile = tn; s = sn; r = rn; ce = cn;
        av0 = av0n; av1 = av1n; bv0 = bv0n; bv1 = bv1n;
        a64u = a64n; b64u = b64n;
    }
}

// ---------------- final: f16 agg -> relu -> f32 out ----------------
__global__ __launch_bounds__(256) void final_kernel(
    const __half2* __restrict__ agg2, float* __restrict__ out)
{
    const int i = blockIdx.x * 256 + threadIdx.x;   // 4 halves per thread
    __half2 h0 = agg2[2 * i];
    __half2 h1 = agg2[2 * i + 1];
    float2 f0 = __half22float2(h0);
    float2 f1 = __half22float2(h1);
    float4 v;
    v.x = fmaxf(f0.x, 0.f); v.y = fmaxf(f0.y, 0.f);
    v.z = fmaxf(f1.x, 0.f); v.w = fmaxf(f1.y, 0.f);
    reinterpret_cast<float4*>(out)[i] = v;
}

__global__ __launch_bounds__(256) void relu_kernel(float* __restrict__ out) {
    const int i = blockIdx.x * 256 + threadIdx.x;
    float4* p = reinterpret_cast<float4*>(out);
    float4 v = p[i];
    v.x = fmaxf(v.x, 0.f); v.y = fmaxf(v.y, 0.f);
    v.z = fmaxf(v.z, 0.f); v.w = fmaxf(v.w, 0.f);
    p[i] = v;
}

// ---------------- fallback (ws too small): monolithic round-1 kernel ----------
__global__ __launch_bounds__(256) void edge_msg_fallback(
    const float* __restrict__ h, const float* __restrict__ coup,
    const float* __restrict__ W1, const float* __restrict__ b1,
    const float* __restrict__ W2, const float* __restrict__ b2,
    const int* __restrict__ senders, const int* __restrict__ receivers,
    float* __restrict__ out)
{
    __shared__ float sW1t[DE * W1_LD];
    __shared__ float sW2[DE * D];
    __shared__ float sb1[DE];
    __shared__ float sb2[D];
    for (int i = threadIdx.x; i < DE * DE; i += 256) {
        int k = i / DE, j = i - k * DE;
        sW1t[j * W1_LD + k] = W1[i];
    }
    for (int i = threadIdx.x; i < DE * D; i += 256) sW2[i] = W2[i];
    if (threadIdx.x < DE) sb1[threadIdx.x] = b1[threadIdx.x];
    if (threadIdx.x >= 128 && threadIdx.x < 128 + D) sb2[threadIdx.x - 128] = b2[threadIdx.x - 128];
    __syncthreads();
    const int e = blockIdx.x * 256 + threadIdx.x;
    const int s = senders[e];
    const int r = receivers[e];
    float edgef[DE];
    const float4* hr = reinterpret_cast<const float4*>(h + (size_t)r * D);
    const float4* hs = reinterpret_cast<const float4*>(h + (size_t)s * D);
    #pragma unroll
    for (int i = 0; i < 8; ++i) {
        float4 v = hr[i];
        edgef[4*i] = v.x; edgef[4*i+1] = v.y; edgef[4*i+2] = v.z; edgef[4*i+3] = v.w;
    }
    #pragma unroll
    for (int i = 0; i < 8; ++i) {
        float4 v = hs[i];
        edgef[D+4*i] = v.x; edgef[D+4*i+1] = v.y; edgef[D+4*i+2] = v.z; edgef[D+4*i+3] = v.w;
    }
    edgef[2*D] = coup[e < NC ? e : e - NC];
    float acc[D];
    #pragma unroll
    for (int d2 = 0; d2 < D; ++d2) acc[d2] = sb2[d2];
    for (int j = 0; j < DE; ++j) {
        const float* wrow = &sW1t[j * W1_LD];
        float p0 = 0.f, p1 = 0.f, p2 = 0.f, p3 = 0.f;
        #pragma unroll
        for (int k = 0; k < 64; k += 4) {
            p0 = fmaf(edgef[k], wrow[k], p0);
            p1 = fmaf(edgef[k+1], wrow[k+1], p1);
            p2 = fmaf(edgef[k+2], wrow[k+2], p2);
            p3 = fmaf(edgef[k+3], wrow[k+3], p3);
        }
        float hj = selu_f(sb1[j] + fmaf(edgef[64], wrow[64], (p0+p1)+(p2+p3)));
        const float* w2row = &sW2[j * D];
        #pragma unroll
        for (int d2 = 0; d2 < D; ++d2) acc[d2] = fmaf(hj, w2row[d2], acc[d2]);
    }
    float* op = out + (size_t)r * D;
    #pragma unroll
    for (int d2 = 0; d2 < D; ++d2) unsafeAtomicAdd(op + d2, selu_f(acc[d2]));
}

extern "C" void kernel_launch(void* const* d_in, const int* in_sizes, int n_in,
                              void* d_out, int out_size, void* d_ws, size_t ws_size,
                              hipStream_t stream) {
    const float* h    = (const float*)d_in[0];
    const float* coup = (const float*)d_in[1];
    const float* W1   = (const float*)d_in[2];
    const float* b1   = (const float*)d_in[3];
    const float* W2   = (const float*)d_in[4];
    const float* b2   = (const float*)d_in[5];
    // d_in[6..9] = Wq, bq, Wk, bk: unused — softmax over a size-1 axis is 1.0
    const int* senders   = (const int*)d_in[10];
    const int* receivers = (const int*)d_in[11];
    float* out = (float*)d_out;

    if (ws_size >= (size_t)WS_NEED) {
        char* ws = (char*)d_ws;
        __hip_bfloat16* Atab = (__hip_bfloat16*)(ws + OFF_A);
        __hip_bfloat16* Btab = (__hip_bfloat16*)(ws + OFF_B);
        unsigned short* A64  = (unsigned short*)(ws + OFF_A64);
        unsigned short* B64  = (unsigned short*)(ws + OFF_B64);
        __half*         agg  = (__half*)(ws + OFF_AGG);

        hipMemsetAsync(agg, 0, (size_t)NN * D * sizeof(__half), stream);
        precompute_kernel<<<NN * JB / 256, 256, 0, stream>>>(h, W1, b1, Atab, Btab);
        precompute64_kernel<<<(NN + 255) / 256, 256, 0, stream>>>(h, W1, b1, A64, B64);
        edge_mfma_kernel<<<2048, 256, 0, stream>>>(
            senders, receivers, coup,
            (const uint4*)Atab, (const uint4*)Btab, A64, B64,
            W1, W2, b2, agg);
        final_kernel<<<NN * D / 4 / 256, 256, 0, stream>>>(
            (const __half2*)agg, out);
    } else {
        hipMemsetAsync(d_out, 0, (size_t)out_size * sizeof(float), stream);
        edge_msg_fallback<<<NE / 256, 256, 0, stream>>>(
            h, coup, W1, b1, W2, b2, senders, receivers, out);
        relu_kernel<<<out_size / 4 / 256, 256, 0, stream>>>(out);
    }
}

// Round 14
// 124.631 us; speedup vs baseline: 2.3784x; 1.6539x over previous
//
#include <hip/hip_runtime.h>
#include <hip/hip_bf16.h>
#include <hip/hip_fp16.h>

#define NN 100000
#define NE 1600000
#define NC 800000
#define D  32
#define DE 65
#define JB 64     // bf16 elements per table row: 128B, line-aligned
#define W1_LD 68  // fallback kernel stride
#define NT (NE / 16)   // 100000 full 16-edge tiles (NE % 16 == 0)

// ---- ws byte offsets (128B-aligned tables) ----
#define OFF_A   0u                  // bf16[NN*64]  A table (b1 folded), 128B rows
#define OFF_B   12800000u           // bf16[NN*64]  B table
#define OFF_A64 25600000u           // bf16[NN]     A j=64 column (b1[64] folded)
#define OFF_B64 25800000u           // bf16[NN]     B j=64 column
#define OFF_AGG 26000000u           // f16[NN*32]   packed-atomic accumulator
#define WS_NEED 32400000u

typedef __attribute__((ext_vector_type(8))) short short8;
typedef __attribute__((ext_vector_type(4))) float f32x4;

__device__ __forceinline__ float selu_f(float x) {
    // branch-free: x>0 -> scale*x ; x<0 -> scale*alpha*(exp(x)-1)
    float p = fmaxf(x, 0.f);
    float m = fminf(x, 0.f);
    return fmaf(1.7580993408473766f, __expf(m) - 1.f, 1.0507009873554805f * p);
}

__device__ __forceinline__ float2 bf2(unsigned int u) {
    // two packed bf16 -> two floats (element 0 in low 16 bits)
    return make_float2(__uint_as_float(u << 16), __uint_as_float(u & 0xffff0000u));
}

__device__ __forceinline__ float bfs(unsigned short u) {
    return __uint_as_float(((unsigned)u) << 16);
}

__device__ __forceinline__ short f2bf(float x) {
    union { __hip_bfloat16 h; short s; } u;
    u.h = __float2bfloat16(x);
    return u.s;
}

__device__ __forceinline__ unsigned short f2bfu(float x) {
    return (unsigned short)f2bf(x);
}

// ---------------- fused MFMA precompute: tables A,B + j=64 columns ----------------
// One wave per 16 nodes. Lane (er=node slot, g=k-octet): H-frag = h[nb+er][8g..8g+7]
// bf16. Per j-block jt: C[node][j] = mfma(H, W1frag) (K=32). C rows=4g+q (node),
// cols=er (j within block). Pair-packed uint stores. j=64 column via fp32 dot +
// shfl_xor reduce (folds old precompute64_kernel).
__global__ __launch_bounds__(256) void precompute_mfma_kernel(
    const float* __restrict__ h, const float* __restrict__ W1,
    const float* __restrict__ b1,
    unsigned* __restrict__ A2, unsigned* __restrict__ B2,
    unsigned short* __restrict__ A64, unsigned short* __restrict__ B64)
{
    const int lane = threadIdx.x & 63;
    const int wid  = threadIdx.x >> 6;
    const int g    = lane >> 4;
    const int er   = lane & 15;
    const int nb   = (blockIdx.x * 4 + wid) * 16;   // 16 nodes per wave
    if (nb >= NN) return;                            // NN % 16 == 0: no partial tiles

    // ---- W1 fragments: WA[jt][i] = W1[8g+i][16jt+er], WB rows k+32 ----
    short8 WA[4], WB[4];
    #pragma unroll
    for (int jt = 0; jt < 4; ++jt)
        #pragma unroll
        for (int i = 0; i < 8; ++i) {
            WA[jt][i] = f2bf(W1[(8 * g + i) * DE + 16 * jt + er]);
            WB[jt][i] = f2bf(W1[(8 * g + i + 32) * DE + 16 * jt + er]);
        }
    float b1v[4];
    #pragma unroll
    for (int jt = 0; jt < 4; ++jt) b1v[jt] = b1[16 * jt + er];
    float wa64[8], wb64[8];
    #pragma unroll
    for (int i = 0; i < 8; ++i) {
        wa64[i] = W1[(8 * g + i) * DE + 64];
        wb64[i] = W1[(8 * g + i + 32) * DE + 64];
    }

    // ---- H fragment: node nb+er, k = 8g..8g+7 ----
    const float4* hp = reinterpret_cast<const float4*>(h + (size_t)(nb + er) * D + 8 * g);
    const float4 h0 = hp[0], h1 = hp[1];
    short8 H;
    H[0] = f2bf(h0.x); H[1] = f2bf(h0.y); H[2] = f2bf(h0.z); H[3] = f2bf(h0.w);
    H[4] = f2bf(h1.x); H[5] = f2bf(h1.y); H[6] = f2bf(h1.z); H[7] = f2bf(h1.w);

    // ---- j=64 columns: fp32 dot, reduced across the 4 g-groups ----
    float pa = 0.f, pb = 0.f;
    pa = fmaf(h0.x, wa64[0], pa); pa = fmaf(h0.y, wa64[1], pa);
    pa = fmaf(h0.z, wa64[2], pa); pa = fmaf(h0.w, wa64[3], pa);
    pa = fmaf(h1.x, wa64[4], pa); pa = fmaf(h1.y, wa64[5], pa);
    pa = fmaf(h1.z, wa64[6], pa); pa = fmaf(h1.w, wa64[7], pa);
    pb = fmaf(h0.x, wb64[0], pb); pb = fmaf(h0.y, wb64[1], pb);
    pb = fmaf(h0.z, wb64[2], pb); pb = fmaf(h0.w, wb64[3], pb);
    pb = fmaf(h1.x, wb64[4], pb); pb = fmaf(h1.y, wb64[5], pb);
    pb = fmaf(h1.z, wb64[6], pb); pb = fmaf(h1.w, wb64[7], pb);
    pa += __shfl_xor(pa, 16); pa += __shfl_xor(pa, 32);
    pb += __shfl_xor(pb, 16); pb += __shfl_xor(pb, 32);
    if (lane < 16) {
        A64[nb + er] = f2bfu(pa + b1[64]);
        B64[nb + er] = f2bfu(pb);
    }

    // ---- 8 MFMAs: both tables for 16 nodes ----
    #pragma unroll
    for (int jt = 0; jt < 4; ++jt) {
        f32x4 Ca = {0.f, 0.f, 0.f, 0.f};
        f32x4 Cb = {0.f, 0.f, 0.f, 0.f};
        Ca = __builtin_amdgcn_mfma_f32_16x16x32_bf16(H, WA[jt], Ca, 0, 0, 0);
        Cb = __builtin_amdgcn_mfma_f32_16x16x32_bf16(H, WB[jt], Cb, 0, 0, 0);
        #pragma unroll
        for (int q = 0; q < 4; ++q) {
            const float va = Ca[q] + b1v[jt];        // fold b1 into A
            const float vb = Cb[q];
            const float va_p = __shfl_xor(va, 1);
            const float vb_p = __shfl_xor(vb, 1);
            if ((er & 1) == 0) {                      // even lane packs (j, j+1)
                const int node = nb + 4 * g + q;
                const unsigned ua = (unsigned)f2bfu(va) | ((unsigned)f2bfu(va_p) << 16);
                const unsigned ub = (unsigned)f2bfu(vb) | ((unsigned)f2bfu(vb_p) << 16);
                A2[(size_t)node * 32 + 8 * jt + (er >> 1)] = ua;
                B2[(size_t)node * 32 + 8 * jt + (er >> 1)] = ub;
            }
        }
    }
}

// ---------------- edge-order MFMA kernel: one wave per 16-edge tile ----------------
// Lane (er=lane&15, g=lane>>4): builds hidden units j=32c+8g+i for edge er (A-frag),
// W2 register-resident B-frags; C/D: col=lane&15 (output dim), row=4g+reg (edge).
// Epilogue: shfl-pair adjacent columns -> packed f16 atomics (2 values / 4B atomic)
// into the f16 agg workspace -> halves the device-scope atomic write stream.
__global__ __launch_bounds__(256) void edge_mfma_kernel(
    const int* __restrict__ senders,
    const int* __restrict__ receivers,
    const float* __restrict__ coup,
    const uint4* __restrict__ Au4,
    const uint4* __restrict__ Bu4,
    const unsigned short* __restrict__ A64,
    const unsigned short* __restrict__ B64,
    const float* __restrict__ W1,
    const float* __restrict__ W2,
    const float* __restrict__ b2,
    __half* __restrict__ agg)
{
    const int lane = threadIdx.x & 63;
    const int g    = lane >> 4;              // k-octet group
    const int er   = lane & 15;              // edge slot / output col

    // ---- per-wave hoisted constants (amortized over ~12 tiles) ----
    float w1c0[8], w1c1[8];
    #pragma unroll
    for (int i = 0; i < 8; ++i) {
        w1c0[i] = W1[64 * DE + 8 * g + i];
        w1c1[i] = W1[64 * DE + 32 + 8 * g + i];
    }
    const float w1c64 = W1[64 * DE + 64];

    short8 WB[2][2];   // WB[chunk][colhalf][i] = W2[32c+8g+i][16hf+er]
    #pragma unroll
    for (int c = 0; c < 2; ++c)
        #pragma unroll
        for (int hf = 0; hf < 2; ++hf)
            #pragma unroll
            for (int i = 0; i < 8; ++i)
                WB[c][hf][i] = f2bf(W2[(32 * c + 8 * g + i) * D + 16 * hf + er]);
    const float w2_64lo = W2[64 * D + er];
    const float w2_64hi = W2[64 * D + 16 + er];
    const float b2lo = b2[er];
    const float b2hi = b2[16 + er];

    int tile = blockIdx.x * 4 + (threadIdx.x >> 6);
    const int stride = gridDim.x * 4;
    if (tile >= NT) return;

    // ---- prologue: indices + gathers for first tile ----
    int e = tile * 16 + er;
    int s = senders[e];
    int r = receivers[e];
    float ce = coup[e < NC ? e : e - NC];
    uint4 av0 = Au4[(size_t)r * 8 + g];
    uint4 av1 = Au4[(size_t)r * 8 + 4 + g];
    uint4 bv0 = Bu4[(size_t)s * 8 + g];
    uint4 bv1 = Bu4[(size_t)s * 8 + 4 + g];
    unsigned short a64u = A64[r];
    unsigned short b64u = B64[s];

    while (true) {
        // ---- prefetch next tile's indices (overlaps current compute) ----
        const int tn = tile + stride;
        const bool more = tn < NT;
        int sn = 0, rn = 0;
        float cn = 0.f;
        if (more) {
            const int en = tn * 16 + er;
            sn = senders[en];
            rn = receivers[en];
            cn = coup[en < NC ? en : en - NC];
        }

        // ---- build A-frags for current tile ----
        short8 A0, A1;
        {
            float2 ta, tb;
            ta = bf2(av0.x); tb = bf2(bv0.x);
            A0[0] = f2bf(selu_f(fmaf(ce, w1c0[0], ta.x + tb.x)));
            A0[1] = f2bf(selu_f(fmaf(ce, w1c0[1], ta.y + tb.y)));
            ta = bf2(av0.y); tb = bf2(bv0.y);
            A0[2] = f2bf(selu_f(fmaf(ce, w1c0[2], ta.x + tb.x)));
            A0[3] = f2bf(selu_f(fmaf(ce, w1c0[3], ta.y + tb.y)));
            ta = bf2(av0.z); tb = bf2(bv0.z);
            A0[4] = f2bf(selu_f(fmaf(ce, w1c0[4], ta.x + tb.x)));
            A0[5] = f2bf(selu_f(fmaf(ce, w1c0[5], ta.y + tb.y)));
            ta = bf2(av0.w); tb = bf2(bv0.w);
            A0[6] = f2bf(selu_f(fmaf(ce, w1c0[6], ta.x + tb.x)));
            A0[7] = f2bf(selu_f(fmaf(ce, w1c0[7], ta.y + tb.y)));
            ta = bf2(av1.x); tb = bf2(bv1.x);
            A1[0] = f2bf(selu_f(fmaf(ce, w1c1[0], ta.x + tb.x)));
            A1[1] = f2bf(selu_f(fmaf(ce, w1c1[1], ta.y + tb.y)));
            ta = bf2(av1.y); tb = bf2(bv1.y);
            A1[2] = f2bf(selu_f(fmaf(ce, w1c1[2], ta.x + tb.x)));
            A1[3] = f2bf(selu_f(fmaf(ce, w1c1[3], ta.y + tb.y)));
            ta = bf2(av1.z); tb = bf2(bv1.z);
            A1[4] = f2bf(selu_f(fmaf(ce, w1c1[4], ta.x + tb.x)));
            A1[5] = f2bf(selu_f(fmaf(ce, w1c1[5], ta.y + tb.y)));
            ta = bf2(av1.w); tb = bf2(bv1.w);
            A1[6] = f2bf(selu_f(fmaf(ce, w1c1[6], ta.x + tb.x)));
            A1[7] = f2bf(selu_f(fmaf(ce, w1c1[7], ta.y + tb.y)));
        }
        const float h64 = selu_f(fmaf(ce, w1c64, bfs(a64u) + bfs(b64u)));
        const int rcur = r;

        // ---- issue next tile's gathers (latency hides under MFMA+epilogue) ----
        uint4 av0n, av1n, bv0n, bv1n;
        unsigned short a64n = 0, b64n = 0;
        if (more) {
            av0n = Au4[(size_t)rn * 8 + g];
            av1n = Au4[(size_t)rn * 8 + 4 + g];
            bv0n = Bu4[(size_t)sn * 8 + g];
            bv1n = Bu4[(size_t)sn * 8 + 4 + g];
            a64n = A64[rn];
            b64n = B64[sn];
        }

        // ---- MFMA: (16 edges) x 32 dims, K=64 ----
        f32x4 Clo = {0.f, 0.f, 0.f, 0.f};
        f32x4 Chi = {0.f, 0.f, 0.f, 0.f};
        Clo = __builtin_amdgcn_mfma_f32_16x16x32_bf16(A0, WB[0][0], Clo, 0, 0, 0);
        Clo = __builtin_amdgcn_mfma_f32_16x16x32_bf16(A1, WB[1][0], Clo, 0, 0, 0);
        Chi = __builtin_amdgcn_mfma_f32_16x16x32_bf16(A0, WB[0][1], Chi, 0, 0, 0);
        Chi = __builtin_amdgcn_mfma_f32_16x16x32_bf16(A1, WB[1][1], Chi, 0, 0, 0);

        // ---- j=64 fold + outer selu + packed-f16 atomic scatter ----
        #pragma unroll
        for (int q = 0; q < 4; ++q) {
            const int m = 4 * g + q;                 // edge slot of C row q
            const float hm = __shfl(h64, m);
            const int   rq = __shfl(rcur, m);
            const float mlo = selu_f(fmaf(hm, w2_64lo, Clo[q]) + b2lo);
            const float mhi = selu_f(fmaf(hm, w2_64hi, Chi[q]) + b2hi);
            const float pl = __shfl_xor(mlo, 1);     // partner column's lo value
            const float ph = __shfl_xor(mhi, 1);     // partner column's hi value
            __half2 val;
            int off;
            if ((er & 1) == 0) {                     // even lane: cols (er, er+1)
                val = __halves2half2(__float2half(mlo), __float2half(pl));
                off = rq * D + er;
            } else {                                 // odd lane: cols (er+15, er+16)
                val = __halves2half2(__float2half(ph), __float2half(mhi));
                off = rq * D + 16 + (er - 1);
            }
            unsafeAtomicAdd(reinterpret_cast<__half2*>(agg + off), val);
        }

        if (!more) break;
        tile = tn; s = sn; r = rn; ce = cn;
        av0 = av0n; av1 = av1n; bv0 = bv0n; bv1 = bv1n;
        a64u = a64n; b64u = b64n;
    }
}

// ---------------- final: f16 agg -> relu -> f32 out ----------------
__global__ __launch_bounds__(256) void final_kernel(
    const __half2* __restrict__ agg2, float* __restrict__ out)
{
    const int i = blockIdx.x * 256 + threadIdx.x;   // 4 halves per thread
    __half2 h0 = agg2[2 * i];
    __half2 h1 = agg2[2 * i + 1];
    float2 f0 = __half22float2(h0);
    float2 f1 = __half22float2(h1);
    float4 v;
    v.x = fmaxf(f0.x, 0.f); v.y = fmaxf(f0.y, 0.f);
    v.z = fmaxf(f1.x, 0.f); v.w = fmaxf(f1.y, 0.f);
    reinterpret_cast<float4*>(out)[i] = v;
}

__global__ __launch_bounds__(256) void relu_kernel(float* __restrict__ out) {
    const int i = blockIdx.x * 256 + threadIdx.x;
    float4* p = reinterpret_cast<float4*>(out);
    float4 v = p[i];
    v.x = fmaxf(v.x, 0.f); v.y = fmaxf(v.y, 0.f);
    v.z = fmaxf(v.z, 0.f); v.w = fmaxf(v.w, 0.f);
    p[i] = v;
}

// ---------------- fallback (ws too small): monolithic round-1 kernel ----------
__global__ __launch_bounds__(256) void edge_msg_fallback(
    const float* __restrict__ h, const float* __restrict__ coup,
    const float* __restrict__ W1, const float* __restrict__ b1,
    const float* __restrict__ W2, const float* __restrict__ b2,
    const int* __restrict__ senders, const int* __restrict__ receivers,
    float* __restrict__ out)
{
    __shared__ float sW1t[DE * W1_LD];
    __shared__ float sW2[DE * D];
    __shared__ float sb1[DE];
    __shared__ float sb2[D];
    for (int i = threadIdx.x; i < DE * DE; i += 256) {
        int k = i / DE, j = i - k * DE;
        sW1t[j * W1_LD + k] = W1[i];
    }
    for (int i = threadIdx.x; i < DE * D; i += 256) sW2[i] = W2[i];
    if (threadIdx.x < DE) sb1[threadIdx.x] = b1[threadIdx.x];
    if (threadIdx.x >= 128 && threadIdx.x < 128 + D) sb2[threadIdx.x - 128] = b2[threadIdx.x - 128];
    __syncthreads();
    const int e = blockIdx.x * 256 + threadIdx.x;
    const int s = senders[e];
    const int r = receivers[e];
    float edgef[DE];
    const float4* hr = reinterpret_cast<const float4*>(h + (size_t)r * D);
    const float4* hs = reinterpret_cast<const float4*>(h + (size_t)s * D);
    #pragma unroll
    for (int i = 0; i < 8; ++i) {
        float4 v = hr[i];
        edgef[4*i] = v.x; edgef[4*i+1] = v.y; edgef[4*i+2] = v.z; edgef[4*i+3] = v.w;
    }
    #pragma unroll
    for (int i = 0; i < 8; ++i) {
        float4 v = hs[i];
        edgef[D+4*i] = v.x; edgef[D+4*i+1] = v.y; edgef[D+4*i+2] = v.z; edgef[D+4*i+3] = v.w;
    }
    edgef[2*D] = coup[e < NC ? e : e - NC];
    float acc[D];
    #pragma unroll
    for (int d2 = 0; d2 < D; ++d2) acc[d2] = sb2[d2];
    for (int j = 0; j < DE; ++j) {
        const float* wrow = &sW1t[j * W1_LD];
        float p0 = 0.f, p1 = 0.f, p2 = 0.f, p3 = 0.f;
        #pragma unroll
        for (int k = 0; k < 64; k += 4) {
            p0 = fmaf(edgef[k], wrow[k], p0);
            p1 = fmaf(edgef[k+1], wrow[k+1], p1);
            p2 = fmaf(edgef[k+2], wrow[k+2], p2);
            p3 = fmaf(edgef[k+3], wrow[k+3], p3);
        }
        float hj = selu_f(sb1[j] + fmaf(edgef[64], wrow[64], (p0+p1)+(p2+p3)));
        const float* w2row = &sW2[j * D];
        #pragma unroll
        for (int d2 = 0; d2 < D; ++d2) acc[d2] = fmaf(hj, w2row[d2], acc[d2]);
    }
    float* op = out + (size_t)r * D;
    #pragma unroll
    for (int d2 = 0; d2 < D; ++d2) unsafeAtomicAdd(op + d2, selu_f(acc[d2]));
}

extern "C" void kernel_launch(void* const* d_in, const int* in_sizes, int n_in,
                              void* d_out, int out_size, void* d_ws, size_t ws_size,
                              hipStream_t stream) {
    const float* h    = (const float*)d_in[0];
    const float* coup = (const float*)d_in[1];
    const float* W1   = (const float*)d_in[2];
    const float* b1   = (const float*)d_in[3];
    const float* W2   = (const float*)d_in[4];
    const float* b2   = (const float*)d_in[5];
    // d_in[6..9] = Wq, bq, Wk, bk: unused — softmax over a size-1 axis is 1.0
    const int* senders   = (const int*)d_in[10];
    const int* receivers = (const int*)d_in[11];
    float* out = (float*)d_out;

    if (ws_size >= (size_t)WS_NEED) {
        char* ws = (char*)d_ws;
        unsigned*       A2   = (unsigned*)(ws + OFF_A);
        unsigned*       B2   = (unsigned*)(ws + OFF_B);
        unsigned short* A64  = (unsigned short*)(ws + OFF_A64);
        unsigned short* B64  = (unsigned short*)(ws + OFF_B64);
        __half*         agg  = (__half*)(ws + OFF_AGG);

        hipMemsetAsync(agg, 0, (size_t)NN * D * sizeof(__half), stream);
        precompute_mfma_kernel<<<(NN + 63) / 64, 256, 0, stream>>>(
            h, W1, b1, A2, B2, A64, B64);
        edge_mfma_kernel<<<2048, 256, 0, stream>>>(
            senders, receivers, coup,
            (const uint4*)(ws + OFF_A), (const uint4*)(ws + OFF_B), A64, B64,
            W1, W2, b2, agg);
        final_kernel<<<NN * D / 4 / 256, 256, 0, stream>>>(
            (const __half2*)agg, out);
    } else {
        hipMemsetAsync(d_out, 0, (size_t)out_size * sizeof(float), stream);
        edge_msg_fallback<<<NE / 256, 256, 0, stream>>>(
            h, coup, W1, b1, W2, b2, senders, receivers, out);
        relu_kernel<<<out_size / 4 / 256, 256, 0, stream>>>(out);
    }
}